// Round 2
// baseline (409.693 us; speedup 1.0000x reference)
//
#include <hip/hip_runtime.h>
#include <hip/hip_bf16.h>
#include <math.h>

// Problem constants (from reference setup_inputs)
#define BB 32
#define TT_N 2048
#define DD 64
#define TP 128   // p-tile (anchors per block)
#define TTILE 64 // t-tile (targets per inner tile)

// ws layout in floats
#define OFF_TIC  0u
#define OFF_NE   (BB*TT_N)                       // 65536
#define OFF_M    (OFF_NE + BB*TT_N*DD)           // 4259840
#define OFF_SINV (OFF_M + BB*DD)                 // 4261888
// total floats = 4327424  (~17.3 MB)

// ---------- kernel 1: per-batch tic max + normalize ----------
__global__ void k_tic(const float* __restrict__ tic, float* __restrict__ tic_n) {
    int b = blockIdx.x;
    const float* row = tic + b * TT_N;
    float m = -1e30f;
    for (int t = threadIdx.x; t < TT_N; t += 256) m = fmaxf(m, row[t]);
    #pragma unroll
    for (int off = 32; off; off >>= 1) m = fmaxf(m, __shfl_xor(m, off));
    __shared__ float red[4];
    if ((threadIdx.x & 63) == 0) red[threadIdx.x >> 6] = m;
    __syncthreads();
    float mm = fmaxf(fmaxf(red[0], red[1]), fmaxf(red[2], red[3]));
    float inv = 1.0f / mm;
    for (int t = threadIdx.x; t < TT_N; t += 256) tic_n[b * TT_N + t] = row[t] * inv;
}

// ---------- kernel 2: L2-normalize embedding rows (one wave per row) ----------
__global__ void k_norm(const float* __restrict__ emb, float* __restrict__ ne) {
    int row  = blockIdx.x * 4 + (threadIdx.x >> 6);
    int lane = threadIdx.x & 63;
    float v  = emb[(size_t)row * DD + lane];
    float ss = v * v;
    #pragma unroll
    for (int off = 32; off; off >>= 1) ss += __shfl_xor(ss, off);
    float nrm = fmaxf(sqrtf(ss), 1e-8f);
    ne[(size_t)row * DD + lane] = v / nrm;
}

// ---------- kernel 3: M[b,d] = sum_t ne[b,t,d]  (M pre-zeroed) ----------
__global__ void k_msum(const float* __restrict__ ne, float* __restrict__ M) {
    int b     = blockIdx.x >> 3;
    int chunk = blockIdx.x & 7;   // 8 chunks of 256 t each
    int d     = threadIdx.x & 63;
    int tg    = threadIdx.x >> 6; // 0..3
    float s = 0.f;
    int t0 = chunk * 256;
    for (int i = tg; i < 256; i += 4)
        s += ne[((size_t)(b * TT_N + t0 + i)) * DD + d];
    __shared__ float red[256];
    red[threadIdx.x] = s;
    __syncthreads();
    if (threadIdx.x < 64) {
        float tot = red[threadIdx.x] + red[threadIdx.x + 64] +
                    red[threadIdx.x + 128] + red[threadIdx.x + 192];
        atomicAdd(&M[b * DD + d], tot);
    }
}

// ---------- kernel 4: sinv[b,p] = 1 / (ne_p . M_b + T)  (one wave per row) ----------
__global__ void k_ssc(const float* __restrict__ ne, const float* __restrict__ M,
                      float* __restrict__ sinv) {
    int row  = blockIdx.x * 4 + (threadIdx.x >> 6);
    int b    = row >> 11;  // / TT_N
    int lane = threadIdx.x & 63;
    float v = ne[(size_t)row * DD + lane] * M[b * DD + lane];
    #pragma unroll
    for (int off = 32; off; off >>= 1) v += __shfl_xor(v, off);
    if (lane == 0) sinv[row] = 1.0f / (v + (float)TT_N);
}

// ---------- main fused GEMM + KL kernel ----------
// grid: (T/TP = 16, B = 32), block 256.  Each block: 128 anchors x all 2048 targets.
__launch_bounds__(256, 2)
__global__ void k_main(const float* __restrict__ ne, const float* __restrict__ tic_n,
                       const float* __restrict__ sinv, float* __restrict__ out) {
    __shared__ float As[DD][TP];     // 32 KB, [k][p]
    __shared__ float Bs[DD][TTILE];  // 16 KB, [k][t]
    __shared__ float tts[TTILE];
    __shared__ float red[16];

    int b   = blockIdx.y;
    int p0  = blockIdx.x * TP;
    int tid = threadIdx.x;
    int ty  = tid >> 4;   // 0..15 -> 8 p-rows each
    int tx  = tid & 15;   // 0..15 -> 4 t-cols each

    // stage A-tile (transpose to [k][p]): 2 threads per row, 32 d's each
    {
        int r     = tid >> 1;
        int dbase = (tid & 1) * 32;
        const float* src = ne + ((size_t)(b * TT_N + p0 + r)) * DD + dbase;
        #pragma unroll
        for (int q = 0; q < 8; ++q) {
            float4 v = *(const float4*)(src + q * 4);
            int k = dbase + q * 4;
            As[k + 0][r] = v.x; As[k + 1][r] = v.y;
            As[k + 2][r] = v.z; As[k + 3][r] = v.w;
        }
    }

    // per-row constants + accumulators
    float tp[8], si[8], SP[8], KA[8];
    #pragma unroll
    for (int i = 0; i < 8; ++i) {
        int p = p0 + ty * 8 + i;
        tp[i] = tic_n[b * TT_N + p];
        si[i] = sinv[b * TT_N + p];
        SP[i] = 0.f; KA[i] = 0.f;
    }

    for (int t0 = 0; t0 < TT_N; t0 += TTILE) {
        __syncthreads();  // previous tile's Bs reads done
        // stage B-tile: 4 threads per row, 16 d's each
        {
            int r     = tid >> 2;
            int dbase = (tid & 3) * 16;
            const float* src = ne + ((size_t)(b * TT_N + t0 + r)) * DD + dbase;
            #pragma unroll
            for (int q = 0; q < 4; ++q) {
                float4 v = *(const float4*)(src + q * 4);
                int k = dbase + q * 4;
                Bs[k + 0][r] = v.x; Bs[k + 1][r] = v.y;
                Bs[k + 2][r] = v.z; Bs[k + 3][r] = v.w;
            }
            if (tid < TTILE) tts[tid] = tic_n[b * TT_N + t0 + tid];
        }
        __syncthreads();

        float acc[8][4];
        #pragma unroll
        for (int i = 0; i < 8; ++i)
            #pragma unroll
            for (int j = 0; j < 4; ++j) acc[i][j] = 0.f;

        #pragma unroll 8
        for (int k = 0; k < DD; ++k) {
            float4 a0 = *(const float4*)&As[k][ty * 8];
            float4 a1 = *(const float4*)&As[k][ty * 8 + 4];
            float4 bv = *(const float4*)&Bs[k][tx * 4];
            float av[8] = {a0.x, a0.y, a0.z, a0.w, a1.x, a1.y, a1.z, a1.w};
            float bb[4] = {bv.x, bv.y, bv.z, bv.w};
            #pragma unroll
            for (int i = 0; i < 8; ++i)
                #pragma unroll
                for (int j = 0; j < 4; ++j)
                    acc[i][j] = fmaf(av[i], bb[j], acc[i][j]);
        }

        float ttv[4];
        #pragma unroll
        for (int j = 0; j < 4; ++j) ttv[j] = tts[tx * 4 + j];

        #pragma unroll
        for (int i = 0; i < 8; ++i) {
            #pragma unroll
            for (int j = 0; j < 4; ++j) {
                float d   = tp[i] - ttv[j];
                float d2h = 0.5f * d * d;
                float e   = __expf(-d2h);
                float sc  = acc[i][j] + 1.0f;           // cosine + 1, in [0,2]
                float lw  = __logf(fmaf(sc, si[i], 1e-6f)); // log(input_w + eps)
                SP[i] += e;
                KA[i] = fmaf(e, (-d2h - lw), KA[i]);
            }
        }
    }

    // reduce partials across the 16 threads (tx) sharing each p-row
    #pragma unroll
    for (int i = 0; i < 8; ++i) {
        #pragma unroll
        for (int off = 1; off < 16; off <<= 1) {
            SP[i] += __shfl_xor(SP[i], off);
            KA[i] += __shfl_xor(KA[i], off);
        }
    }

    float rsum = 0.f;
    if (tx == 0) {
        #pragma unroll
        for (int i = 0; i < 8; ++i)
            rsum += KA[i] / SP[i] - __logf(SP[i]);
        red[ty] = rsum;
    }
    __syncthreads();
    if (tid == 0) {
        float tot = 0.f;
        #pragma unroll
        for (int i = 0; i < 16; ++i) tot += red[i];
        atomicAdd(out, tot * (1.0f / 65536.0f));  // / (B * P)
    }
}

extern "C" void kernel_launch(void* const* d_in, const int* in_sizes, int n_in,
                              void* d_out, int out_size, void* d_ws, size_t ws_size,
                              hipStream_t stream) {
    const float* emb = (const float*)d_in[0];  // [B, T, D]
    const float* tic = (const float*)d_in[1];  // [B, T]
    float* out = (float*)d_out;
    float* ws  = (float*)d_ws;

    float* tic_n = ws + OFF_TIC;
    float* ne    = ws + OFF_NE;
    float* M     = ws + OFF_M;
    float* sinv  = ws + OFF_SINV;

    hipMemsetAsync(out, 0, sizeof(float), stream);
    hipMemsetAsync(M, 0, BB * DD * sizeof(float), stream);

    k_tic<<<BB, 256, 0, stream>>>(tic, tic_n);
    k_norm<<<(BB * TT_N) / 4, 256, 0, stream>>>(emb, ne);
    k_msum<<<BB * 8, 256, 0, stream>>>(ne, M);
    k_ssc<<<(BB * TT_N) / 4, 256, 0, stream>>>(ne, M, sinv);
    k_main<<<dim3(TT_N / TP, BB), 256, 0, stream>>>(ne, tic_n, sinv, out);
}

// Round 3
// 219.008 us; speedup vs baseline: 1.8707x; 1.8707x over previous
//
#include <hip/hip_runtime.h>
#include <hip/hip_bf16.h>
#include <math.h>

// Problem constants
#define BB 32
#define TT 2048
#define DD 64

typedef __attribute__((ext_vector_type(8))) short s16x8;   // 8 bf16 (4 VGPRs) — MFMA A/B frag
typedef __attribute__((ext_vector_type(4))) float f32x4;   // MFMA C/D frag

// ws layout (bytes)
#define OFF_TIC  0u                      // float[32*2048]   = 262144 B
#define OFF_SINV 262144u                 // float[32*2048]   = 262144 B
#define OFF_M    524288u                 // float[32*64]     = 8192 B
#define OFF_HI   532480u                 // ushort[32*2048*64] = 8388608 B
#define OFF_LO   8921088u                // ushort[32*2048*64] = 8388608 B
// total 17309696 B (~17.3 MB)

__device__ __forceinline__ float bf2f(unsigned short u) {
    union { unsigned int i; float f; } c; c.i = ((unsigned int)u) << 16; return c.f;
}
__device__ __forceinline__ unsigned short f2bf(float f) {   // RNE
    union { float f; unsigned int i; } c; c.f = f;
    unsigned int lsb = (c.i >> 16) & 1u;
    c.i += 0x7fffu + lsb;
    return (unsigned short)(c.i >> 16);
}

// ---------- kernel 1: per-batch tic max + normalize ----------
__global__ void k_tic(const float* __restrict__ tic, float* __restrict__ tic_n) {
    int b = blockIdx.x;
    const float* row = tic + b * TT;
    float m = -1e30f;
    for (int t = threadIdx.x; t < TT; t += 256) m = fmaxf(m, row[t]);
    #pragma unroll
    for (int off = 32; off; off >>= 1) m = fmaxf(m, __shfl_xor(m, off));
    __shared__ float red[4];
    if ((threadIdx.x & 63) == 0) red[threadIdx.x >> 6] = m;
    __syncthreads();
    float mm = fmaxf(fmaxf(red[0], red[1]), fmaxf(red[2], red[3]));
    float inv = 1.0f / mm;
    for (int t = threadIdx.x; t < TT; t += 256) tic_n[b * TT + t] = row[t] * inv;
}

// ---------- kernel 2: L2-normalize rows -> bf16 hi/lo split ----------
__global__ void k_norm(const float* __restrict__ emb,
                       unsigned short* __restrict__ hi, unsigned short* __restrict__ lo) {
    int row  = blockIdx.x * 4 + (threadIdx.x >> 6);
    int lane = threadIdx.x & 63;
    float v  = emb[(size_t)row * DD + lane];
    float ss = v * v;
    #pragma unroll
    for (int off = 32; off; off >>= 1) ss += __shfl_xor(ss, off);
    float nrm = fmaxf(sqrtf(ss), 1e-8f);
    float nv  = v / nrm;
    unsigned short h = f2bf(nv);
    hi[(size_t)row * DD + lane] = h;
    lo[(size_t)row * DD + lane] = f2bf(nv - bf2f(h));
}

// ---------- kernel 3: M[b,d] = sum_t ne[b,t,d]  (M pre-zeroed) ----------
__global__ void k_msum(const unsigned short* __restrict__ hi,
                       const unsigned short* __restrict__ lo, float* __restrict__ M) {
    int b     = blockIdx.x >> 3;
    int chunk = blockIdx.x & 7;
    int d     = threadIdx.x & 63;
    int tg    = threadIdx.x >> 6;
    float s = 0.f;
    int t0 = chunk * 256;
    for (int i = tg; i < 256; i += 4) {
        size_t idx = ((size_t)(b * TT + t0 + i)) * DD + d;
        s += bf2f(hi[idx]) + bf2f(lo[idx]);
    }
    __shared__ float red[256];
    red[threadIdx.x] = s;
    __syncthreads();
    if (threadIdx.x < 64) {
        float tot = red[threadIdx.x] + red[threadIdx.x + 64] +
                    red[threadIdx.x + 128] + red[threadIdx.x + 192];
        atomicAdd(&M[b * DD + d], tot);
    }
}

// ---------- kernel 4: sinv[b,p] = 1 / (ne_p . M_b + T) ----------
__global__ void k_ssc(const unsigned short* __restrict__ hi,
                      const unsigned short* __restrict__ lo,
                      const float* __restrict__ M, float* __restrict__ sinv) {
    int row  = blockIdx.x * 4 + (threadIdx.x >> 6);
    int b    = row >> 11;
    int lane = threadIdx.x & 63;
    size_t idx = (size_t)row * DD + lane;
    float v = (bf2f(hi[idx]) + bf2f(lo[idx])) * M[b * DD + lane];
    #pragma unroll
    for (int off = 32; off; off >>= 1) v += __shfl_xor(v, off);
    if (lane == 0) sinv[row] = 1.0f / (v + (float)TT);
}

// ---------- main: MFMA GEMM (bf16 hi/lo x3) + fused KL epilogue ----------
// grid (8, 32), 512 threads = 8 waves. Wave owns 32 p-rows (2 m-frags), block 256 rows.
// t swept in 64-wide tiles staged to XOR-swizzled LDS.
__launch_bounds__(512, 2)
__global__ void k_main(const unsigned short* __restrict__ hi,
                       const unsigned short* __restrict__ lo,
                       const float* __restrict__ tic_n,
                       const float* __restrict__ sinv,
                       float* __restrict__ out) {
    __shared__ unsigned short Bh[64 * 64];   // 8 KB, swizzled [t][d]
    __shared__ unsigned short Bl[64 * 64];   // 8 KB
    __shared__ float tts[64];
    __shared__ float redbuf[8];

    int b   = blockIdx.y;
    int p0  = blockIdx.x * 256;
    int tid = threadIdx.x;
    int w   = tid >> 6;
    int l   = tid & 63;
    int lr  = l & 15;   // row/col within fragment
    int lg  = l >> 4;   // k-group (A/B), row-group (C)

    // --- persistent A fragments: rows p0 + w*32 + mi*16 + lr, k = ks*32 + lg*8 ---
    s16x8 Ah[2][2], Al[2][2];
    #pragma unroll
    for (int mi = 0; mi < 2; ++mi)
        #pragma unroll
        for (int ks = 0; ks < 2; ++ks) {
            size_t off = ((size_t)(b * TT + p0 + w * 32 + mi * 16 + lr)) * DD + ks * 32 + lg * 8;
            Ah[mi][ks] = *(const s16x8*)(hi + off);
            Al[mi][ks] = *(const s16x8*)(lo + off);
        }

    // --- per-row constants (C rows this lane owns: mi*16 + lg*4 + r) ---
    float tp[2][4], si[2][4], SP[2][4], KA[2][4];
    #pragma unroll
    for (int mi = 0; mi < 2; ++mi)
        #pragma unroll
        for (int r = 0; r < 4; ++r) {
            int p = p0 + w * 32 + mi * 16 + lg * 4 + r;
            tp[mi][r] = tic_n[b * TT + p];
            si[mi][r] = sinv[b * TT + p];
            SP[mi][r] = 0.f; KA[mi][r] = 0.f;
        }

    for (int t0 = 0; t0 < TT; t0 += 64) {
        __syncthreads();   // previous tile's frag reads done
        // --- stage B-tile (64 t x 64 d, hi+lo), XOR-swizzled 16B chunks ---
        {
            int r  = tid >> 3;          // 0..63 t-row
            int kc = tid & 7;           // 16B chunk within row
            size_t g = ((size_t)(b * TT + t0 + r)) * DD + kc * 8;
            int dst = r * 64 + ((kc ^ (r & 7)) << 3);
            *(s16x8*)&Bh[dst] = *(const s16x8*)(hi + g);
            *(s16x8*)&Bl[dst] = *(const s16x8*)(lo + g);
            if (tid < 64) tts[tid] = tic_n[b * TT + t0 + tid];
        }
        __syncthreads();

        // --- load B fragments: col = ni*16 + lr, k = ks*32 + lg*8 ---
        s16x8 Fh[4][2], Fl[4][2];
        #pragma unroll
        for (int ni = 0; ni < 4; ++ni) {
            int rB = ni * 16 + lr;
            #pragma unroll
            for (int ks = 0; ks < 2; ++ks) {
                int kc  = ks * 4 + lg;
                int off = rB * 64 + ((kc ^ (rB & 7)) << 3);
                Fh[ni][ks] = *(const s16x8*)&Bh[off];
                Fl[ni][ks] = *(const s16x8*)&Bl[off];
            }
        }

        // --- MFMA: acc = hi.hi + lo.hi + hi.lo  (fp32-accurate dot) ---
        f32x4 acc[2][4];
        #pragma unroll
        for (int mi = 0; mi < 2; ++mi)
            #pragma unroll
            for (int ni = 0; ni < 4; ++ni) {
                f32x4 a = {0.f, 0.f, 0.f, 0.f};
                a = __builtin_amdgcn_mfma_f32_16x16x32_bf16(Ah[mi][0], Fh[ni][0], a, 0, 0, 0);
                a = __builtin_amdgcn_mfma_f32_16x16x32_bf16(Ah[mi][1], Fh[ni][1], a, 0, 0, 0);
                a = __builtin_amdgcn_mfma_f32_16x16x32_bf16(Al[mi][0], Fh[ni][0], a, 0, 0, 0);
                a = __builtin_amdgcn_mfma_f32_16x16x32_bf16(Al[mi][1], Fh[ni][1], a, 0, 0, 0);
                a = __builtin_amdgcn_mfma_f32_16x16x32_bf16(Ah[mi][0], Fl[ni][0], a, 0, 0, 0);
                a = __builtin_amdgcn_mfma_f32_16x16x32_bf16(Ah[mi][1], Fl[ni][1], a, 0, 0, 0);
                acc[mi][ni] = a;
            }

        // --- fused KL epilogue; C element (mi,ni,r): row=mi*16+lg*4+r, col=ni*16+lr ---
        float tt[4];
        #pragma unroll
        for (int ni = 0; ni < 4; ++ni) tt[ni] = tts[ni * 16 + lr];

        #pragma unroll
        for (int mi = 0; mi < 2; ++mi)
            #pragma unroll
            for (int ni = 0; ni < 4; ++ni)
                #pragma unroll
                for (int r = 0; r < 4; ++r) {
                    float d   = tp[mi][r] - tt[ni];
                    float d2h = 0.5f * d * d;
                    float e   = __expf(-d2h);
                    float sc  = acc[mi][ni][r] + 1.0f;
                    float lw  = __logf(fmaf(sc, si[mi][r], 1e-6f));
                    SP[mi][r] += e;
                    KA[mi][r] = fmaf(e, -d2h - lw, KA[mi][r]);
                }
    }

    // --- reduce over cols: lanes 0..15 within each k-group hold partial sums ---
    #pragma unroll
    for (int mi = 0; mi < 2; ++mi)
        #pragma unroll
        for (int r = 0; r < 4; ++r) {
            #pragma unroll
            for (int off = 1; off < 16; off <<= 1) {
                SP[mi][r] += __shfl_xor(SP[mi][r], off);
                KA[mi][r] += __shfl_xor(KA[mi][r], off);
            }
        }

    // per-lane: sum of this group's 8 rows (identical across the 16 lanes of a group)
    float rows = 0.f;
    #pragma unroll
    for (int mi = 0; mi < 2; ++mi)
        #pragma unroll
        for (int r = 0; r < 4; ++r)
            rows += KA[mi][r] / SP[mi][r] - __logf(SP[mi][r]);
    // sum the 4 groups (one representative each via xor-16/32)
    rows += __shfl_xor(rows, 16);
    rows += __shfl_xor(rows, 32);
    if (l == 0) redbuf[w] = rows;
    __syncthreads();
    if (tid == 0) {
        float tot = 0.f;
        #pragma unroll
        for (int i = 0; i < 8; ++i) tot += redbuf[i];
        atomicAdd(out, tot * (1.0f / 65536.0f));   // / (B * P)
    }
}

extern "C" void kernel_launch(void* const* d_in, const int* in_sizes, int n_in,
                              void* d_out, int out_size, void* d_ws, size_t ws_size,
                              hipStream_t stream) {
    const float* emb = (const float*)d_in[0];  // [B, T, D] fp32
    const float* tic = (const float*)d_in[1];  // [B, T] fp32
    float* out = (float*)d_out;
    char*  ws  = (char*)d_ws;

    float*          tic_n = (float*)(ws + OFF_TIC);
    float*          sinv  = (float*)(ws + OFF_SINV);
    float*          M     = (float*)(ws + OFF_M);
    unsigned short* hi    = (unsigned short*)(ws + OFF_HI);
    unsigned short* lo    = (unsigned short*)(ws + OFF_LO);

    hipMemsetAsync(out, 0, sizeof(float), stream);
    hipMemsetAsync(M, 0, BB * DD * sizeof(float), stream);

    k_tic <<<BB, 256, 0, stream>>>(tic, tic_n);
    k_norm<<<(BB * TT) / 4, 256, 0, stream>>>(emb, hi, lo);
    k_msum<<<BB * 8, 256, 0, stream>>>(hi, lo, M);
    k_ssc <<<(BB * TT) / 4, 256, 0, stream>>>(hi, lo, M, sinv);
    k_main<<<dim3(8, BB), 512, 0, stream>>>(hi, lo, tic_n, sinv, out);
}

// Round 4
// 177.490 us; speedup vs baseline: 2.3083x; 1.2339x over previous
//
#include <hip/hip_runtime.h>
#include <hip/hip_bf16.h>
#include <math.h>

// Problem constants
#define BB 32
#define TT 2048
#define DD 64
#define NCHUNK 2
#define TCH (TT / NCHUNK)           // t-range per block (1024)
#define LOG2E 1.4426950408889634f
#define C2    0.7213475204444817f   // log2(e)/2
#define LN2   0.6931471805599453f

typedef __attribute__((ext_vector_type(8))) short s16x8;   // 8 bf16 (4 VGPRs)
typedef __attribute__((ext_vector_type(4))) float f32x4;   // MFMA C/D frag

// ws layout (bytes)
#define OFF_M    0u                         // float[32*64]        = 8 KB
#define OFF_HI   8192u                      // ushort[32*2048*64]  = 8 MB
#define OFF_LO   (8192u + 8388608u)         // ushort[32*2048*64]  = 8 MB
#define OFF_PART (8192u + 16777216u)        // float2[NCHUNK*65536]= 1 MB
// total ~17.8 MB

__device__ __forceinline__ float bf2f(unsigned short u) {
    union { unsigned int i; float f; } c; c.i = ((unsigned int)u) << 16; return c.f;
}
__device__ __forceinline__ unsigned short f2bf(float f) {   // RNE
    union { float f; unsigned int i; } c; c.f = f;
    unsigned int lsb = (c.i >> 16) & 1u;
    c.i += 0x7fffu + lsb;
    return (unsigned short)(c.i >> 16);
}
__device__ __forceinline__ float fexp2(float x) {   // 2^x, single v_exp_f32
    float r; asm("v_exp_f32 %0, %1" : "=v"(r) : "v"(x)); return r;
}
__device__ __forceinline__ float flog2(float x) {   // log2(x), single v_log_f32
    float r; asm("v_log_f32 %0, %1" : "=v"(r) : "v"(x)); return r;
}

// ---------- kernel 1: L2-normalize rows -> bf16 hi/lo split ----------
__global__ void k_norm(const float* __restrict__ emb,
                       unsigned short* __restrict__ hi, unsigned short* __restrict__ lo) {
    int row  = blockIdx.x * 4 + (threadIdx.x >> 6);
    int lane = threadIdx.x & 63;
    float v  = emb[(size_t)row * DD + lane];
    float ss = v * v;
    #pragma unroll
    for (int off = 32; off; off >>= 1) ss += __shfl_xor(ss, off);
    float nrm = fmaxf(sqrtf(ss), 1e-8f);
    float nv  = v / nrm;
    unsigned short h = f2bf(nv);
    hi[(size_t)row * DD + lane] = h;
    lo[(size_t)row * DD + lane] = f2bf(nv - bf2f(h));
}

// ---------- kernel 2: M[b,d] = sum_t ne[b,t,d]  (M pre-zeroed) ----------
__global__ void k_msum(const unsigned short* __restrict__ hi,
                       const unsigned short* __restrict__ lo, float* __restrict__ M) {
    int b     = blockIdx.x >> 3;
    int chunk = blockIdx.x & 7;
    int d     = threadIdx.x & 63;
    int tg    = threadIdx.x >> 6;
    float s = 0.f;
    int t0 = chunk * 256;
    for (int i = tg; i < 256; i += 4) {
        size_t idx = ((size_t)(b * TT + t0 + i)) * DD + d;
        s += bf2f(hi[idx]) + bf2f(lo[idx]);
    }
    __shared__ float red[256];
    red[threadIdx.x] = s;
    __syncthreads();
    if (threadIdx.x < 64) {
        float tot = red[threadIdx.x] + red[threadIdx.x + 64] +
                    red[threadIdx.x + 128] + red[threadIdx.x + 192];
        atomicAdd(&M[b * DD + d], tot);
    }
}

// ---------- kernel 3: MFMA GEMM + fused KL epilogue, t-split partials ----------
// grid (16, 32): x = px*2 + chunk. 512 threads = 8 waves; wave owns 32 p-rows.
__launch_bounds__(512, 4)
__global__ void k_main(const unsigned short* __restrict__ hi,
                       const unsigned short* __restrict__ lo,
                       const float* __restrict__ tic,
                       const float* __restrict__ M,
                       float2* __restrict__ part) {
    __shared__ unsigned short Bh[64 * 64];   // 8 KB, swizzled [t][d]
    __shared__ unsigned short Bl[64 * 64];   // 8 KB
    __shared__ float ticrow[TT];             // 8 KB, normalized tic for this b
    __shared__ float Msh[DD];
    __shared__ float wred[8];

    const int b     = blockIdx.y;
    const int px    = blockIdx.x >> 1;
    const int chunk = blockIdx.x & 1;
    const int p0    = px * 256;
    const int tbase = chunk * TCH;
    const int tid   = threadIdx.x;
    const int w     = tid >> 6;
    const int l     = tid & 63;
    const int lr    = l & 15;   // row/col within fragment
    const int lg    = l >> 4;   // k-group (A/B), row-group (C)

    // --- tic row: load + per-b max + normalize (in LDS) ---
    float m = -1e30f;
    for (int t = tid; t < TT; t += 512) {
        float v = tic[b * TT + t];
        ticrow[t] = v;
        m = fmaxf(m, v);
    }
    #pragma unroll
    for (int off = 32; off; off >>= 1) m = fmaxf(m, __shfl_xor(m, off));
    if (l == 0) wred[w] = m;
    if (tid < DD) Msh[tid] = M[b * DD + tid];
    __syncthreads();
    float mm = wred[0];
    #pragma unroll
    for (int i = 1; i < 8; ++i) mm = fmaxf(mm, wred[i]);
    float inv = 1.0f / mm;
    for (int t = tid; t < TT; t += 512) ticrow[t] *= inv;  // each thread rescales its own writes

    // --- persistent A fragments: rows p0 + w*32 + mi*16 + lr, k = ks*32 + lg*8 ---
    s16x8 Ah[2][2], Al[2][2];
    #pragma unroll
    for (int mi = 0; mi < 2; ++mi)
        #pragma unroll
        for (int ks = 0; ks < 2; ++ks) {
            size_t off = ((size_t)(b * TT + p0 + w * 32 + mi * 16 + lr)) * DD + ks * 32 + lg * 8;
            Ah[mi][ks] = *(const s16x8*)(hi + off);
            Al[mi][ks] = *(const s16x8*)(lo + off);
        }

    __syncthreads();   // normalized ticrow + Msh visible

    // --- sinv for this wave's rows: dot(ne_p, M) from A-frags ---
    float mv[16];
    *(float4*)&mv[0]  = *(const float4*)&Msh[lg * 8];
    *(float4*)&mv[4]  = *(const float4*)&Msh[lg * 8 + 4];
    *(float4*)&mv[8]  = *(const float4*)&Msh[32 + lg * 8];
    *(float4*)&mv[12] = *(const float4*)&Msh[32 + lg * 8 + 4];
    float dotv[2];
    #pragma unroll
    for (int mi = 0; mi < 2; ++mi) {
        float s = 0.f;
        #pragma unroll
        for (int ks = 0; ks < 2; ++ks)
            #pragma unroll
            for (int e = 0; e < 8; ++e) {
                float av = bf2f((unsigned short)Ah[mi][ks][e]) +
                           bf2f((unsigned short)Al[mi][ks][e]);
                s = fmaf(av, mv[ks * 8 + e], s);
            }
        s += __shfl_xor(s, 16);
        s += __shfl_xor(s, 32);
        dotv[mi] = s;   // full dot for row mi*16 + lr (all lg-groups agree)
    }

    // --- per-row (C-layout rows mi*16 + lg*4 + rr) constants ---
    float a_[2][4], b_[2][4], si_[2][4], sip_[2][4], SP[2][4], KA[2][4];
    #pragma unroll
    for (int mi = 0; mi < 2; ++mi)
        #pragma unroll
        for (int rr = 0; rr < 4; ++rr) {
            float dv = __shfl(dotv[mi], lg * 4 + rr);
            float si = 1.0f / (dv + (float)TT);
            si_[mi][rr]  = si;
            sip_[mi][rr] = si + 1e-6f;
            float tp = ticrow[p0 + w * 32 + mi * 16 + lg * 4 + rr];
            a_[mi][rr] = -C2 * tp * tp;
            b_[mi][rr] = LOG2E * tp;
            SP[mi][rr] = 0.f; KA[mi][rr] = 0.f;
        }

    // --- t-loop over this block's chunk ---
    for (int tile = 0; tile < TCH / 64; ++tile) {
        const int t0 = tbase + tile * 64;
        __syncthreads();   // previous tile's frag reads done
        {   // stage B-tile (64 t x 64 d, hi+lo), XOR-swizzled 16B chunks
            int r  = tid >> 3;
            int kc = tid & 7;
            size_t g = ((size_t)(b * TT + t0 + r)) * DD + kc * 8;
            int dst = r * 64 + ((kc ^ (r & 7)) << 3);
            *(s16x8*)&Bh[dst] = *(const s16x8*)(hi + g);
            *(s16x8*)&Bl[dst] = *(const s16x8*)(lo + g);
        }
        __syncthreads();

        // B fragments: col = ni*16 + lr, k = ks*32 + lg*8
        s16x8 Fh[4][2], Fl[4][2];
        #pragma unroll
        for (int ni = 0; ni < 4; ++ni) {
            int rB = ni * 16 + lr;
            #pragma unroll
            for (int ks = 0; ks < 2; ++ks) {
                int kc  = ks * 4 + lg;
                int off = rB * 64 + ((kc ^ (rB & 7)) << 3);
                Fh[ni][ks] = *(const s16x8*)&Bh[off];
                Fl[ni][ks] = *(const s16x8*)&Bl[off];
            }
        }

        // MFMA: acc = hi.hi + lo.hi + hi.lo (fp32-accurate cosine)
        f32x4 acc[2][4];
        #pragma unroll
        for (int mi = 0; mi < 2; ++mi)
            #pragma unroll
            for (int ni = 0; ni < 4; ++ni) {
                f32x4 a = {0.f, 0.f, 0.f, 0.f};
                a = __builtin_amdgcn_mfma_f32_16x16x32_bf16(Ah[mi][0], Fh[ni][0], a, 0, 0, 0);
                a = __builtin_amdgcn_mfma_f32_16x16x32_bf16(Ah[mi][1], Fh[ni][1], a, 0, 0, 0);
                a = __builtin_amdgcn_mfma_f32_16x16x32_bf16(Al[mi][0], Fh[ni][0], a, 0, 0, 0);
                a = __builtin_amdgcn_mfma_f32_16x16x32_bf16(Al[mi][1], Fh[ni][1], a, 0, 0, 0);
                a = __builtin_amdgcn_mfma_f32_16x16x32_bf16(Ah[mi][0], Fl[ni][0], a, 0, 0, 0);
                a = __builtin_amdgcn_mfma_f32_16x16x32_bf16(Ah[mi][1], Fl[ni][1], a, 0, 0, 0);
                acc[mi][ni] = a;
            }

        // per-col consts
        float tt[4], qq[4];
        #pragma unroll
        for (int ni = 0; ni < 4; ++ni) {
            tt[ni] = ticrow[t0 + ni * 16 + lr];
            qq[ni] = (-C2 * tt[ni]) * tt[ni];
        }

        // fused KL epilogue (base-2): 6 VALU + 2 trans per element
        #pragma unroll
        for (int mi = 0; mi < 2; ++mi)
            #pragma unroll
            for (int ni = 0; ni < 4; ++ni)
                #pragma unroll
                for (int r = 0; r < 4; ++r) {
                    float arg = fmaf(b_[mi][r], tt[ni], a_[mi][r]) + qq[ni]; // -d^2/2 * log2e
                    float e   = fexp2(arg);                                  // exp(-d^2/2)
                    float x   = fmaf(acc[mi][ni][r], si_[mi][r], sip_[mi][r]); // (cos+1)*si + eps
                    float l2  = flog2(x);
                    SP[mi][r] += e;
                    KA[mi][r] = fmaf(e, arg - l2, KA[mi][r]);                // base-2 units
                }
    }

    // --- reduce over the 16 cols-lanes of each k-group, write partials ---
    #pragma unroll
    for (int mi = 0; mi < 2; ++mi)
        #pragma unroll
        for (int rr = 0; rr < 4; ++rr) {
            #pragma unroll
            for (int off = 1; off < 16; off <<= 1) {
                SP[mi][rr] += __shfl_xor(SP[mi][rr], off);
                KA[mi][rr] += __shfl_xor(KA[mi][rr], off);
            }
        }
    if (lr == 0) {   // lanes 0,16,32,48 -> lg = 0..3
        #pragma unroll
        for (int mi = 0; mi < 2; ++mi)
            #pragma unroll
            for (int rr = 0; rr < 4; ++rr) {
                int p = p0 + w * 32 + mi * 16 + lg * 4 + rr;
                part[(size_t)chunk * (BB * TT) + b * TT + p] =
                    make_float2(SP[mi][rr], KA[mi][rr]);
            }
    }
}

// ---------- kernel 4: combine partials, nonlinear reduce ----------
__global__ void k_fin(const float2* __restrict__ part, float* __restrict__ out) {
    int g = blockIdx.x * 256 + threadIdx.x;   // 0..65535 = b*TT + p
    float2 q0 = part[g];
    float2 q1 = part[BB * TT + g];
    float SP  = q0.x + q1.x;
    float KA2 = q0.y + q1.y;
    float R = LN2 * (KA2 / SP) - __logf(SP);
    #pragma unroll
    for (int off = 32; off; off >>= 1) R += __shfl_xor(R, off);
    __shared__ float rb[4];
    if ((threadIdx.x & 63) == 0) rb[threadIdx.x >> 6] = R;
    __syncthreads();
    if (threadIdx.x == 0)
        atomicAdd(out, (rb[0] + rb[1] + rb[2] + rb[3]) * (1.0f / 65536.0f));
}

extern "C" void kernel_launch(void* const* d_in, const int* in_sizes, int n_in,
                              void* d_out, int out_size, void* d_ws, size_t ws_size,
                              hipStream_t stream) {
    const float* emb = (const float*)d_in[0];  // [B, T, D] fp32
    const float* tic = (const float*)d_in[1];  // [B, T] fp32
    float* out = (float*)d_out;
    char*  ws  = (char*)d_ws;

    float*          M    = (float*)(ws + OFF_M);
    unsigned short* hi   = (unsigned short*)(ws + OFF_HI);
    unsigned short* lo   = (unsigned short*)(ws + OFF_LO);
    float2*         part = (float2*)(ws + OFF_PART);

    hipMemsetAsync(out, 0, sizeof(float), stream);
    hipMemsetAsync(M, 0, BB * DD * sizeof(float), stream);

    k_norm<<<(BB * TT) / 4, 256, 0, stream>>>(emb, hi, lo);
    k_msum<<<BB * 8, 256, 0, stream>>>(hi, lo, M);
    k_main<<<dim3(2 * (TT / 256), BB), 512, 0, stream>>>(hi, lo, tic, M, part);
    k_fin <<<(BB * TT) / 256, 256, 0, stream>>>(part, out);
}